// Round 27
// baseline (163.593 us; speedup 1.0000x reference)
//
#include <hip/hip_runtime.h>

#define N_NODES 10000
#define N_EDGES 160000
#define FNODE 8
#define C 24
#define HID 16
#define TW (5 * C)    // 120: per-node T row = [f=0..3 ea-weighted][f=4 bias part]
#define NB_L 625      // 625*16 nodes, 625*256 edges exact
#define CAP 64        // ELL capacity; P(Poisson(16) >= 64) ~ 1e-17
#define OVF_MAX 256

// Module-owned scratch. Invariants at call entry: g_cnt == 0 (zero-init at
// load; layer_head re-zeros AFTER a barrier), g_ovf_cnt == 0 (head2 re-zeros).
// Everything else fully rewritten every call. No device-scope fences anywhere.
__device__ int    g_cnt[N_NODES];
__device__ int    g_ell_src[N_NODES * CAP];   // premultiplied: src * TW
__device__ float4 g_ell_ea[N_NODES * CAP];
__device__ int    g_ovf_cnt;
__device__ int    g_ovf_d[OVF_MAX];
__device__ int    g_ovf_src[OVF_MAX];         // premultiplied: src * TW
__device__ float4 g_ovf_ea[OVF_MAX];
__device__ float  g_TA[N_NODES * TW];
__device__ float  g_TB[N_NODES * TW];
__device__ float  g_hA[N_NODES * C];
__device__ float  g_hB[N_NODES * C];
__device__ float  g_partial[NB_L * HID];

// ---------- 1. ELL build (edge binning) + tmat0 (packed-LDS), one dispatch ----------
__global__ void __launch_bounds__(256)
build_tmat_kernel(const int* __restrict__ src, const int* __restrict__ dst,
                  const float* __restrict__ ea, const float* __restrict__ x,
                  const float* __restrict__ few, const float* __restrict__ feb,
                  float* __restrict__ T) {
    __shared__ float4 sW4[FNODE * C];   // [i][o] -> {W_f0,W_f1,W_f2,W_f3}
    __shared__ float  sW1[FNODE * C];   // [i][o] -> bias-proj slice
    __shared__ float  sx[16][FNODE];
    const int tid = threadIdx.x;
    const int b = blockIdx.x;
    for (int idx = tid; idx < FNODE * C; idx += 256) {
        sW4[idx] = make_float4(few[0 * FNODE * C + idx], few[1 * FNODE * C + idx],
                               few[2 * FNODE * C + idx], few[3 * FNODE * C + idx]);
        sW1[idx] = feb[idx];
    }
    const int n0 = b * 16;                  // 625*16 == N_NODES exact
    if (tid < 16 * FNODE) sx[tid / FNODE][tid % FNODE] = x[n0 * FNODE + tid];

    const int e = b * 256 + tid;            // 625*256 == N_EDGES exact
    const int d = dst[e];
    const int slot = atomicAdd(&g_cnt[d], 1);
    if (slot < CAP) {
        g_ell_src[d * CAP + slot] = src[e] * TW;
        g_ell_ea[d * CAP + slot] = ((const float4*)ea)[e];
    } else {
        const int p = atomicAdd(&g_ovf_cnt, 1);
        if (p < OVF_MAX) {
            g_ovf_d[p] = d;
            g_ovf_src[p] = src[e] * TW;
            g_ovf_ea[p] = ((const float4*)ea)[e];
        }
    }
    __syncthreads();
    for (int pr = tid; pr < 16 * C; pr += 256) {
        const int ln = pr / C, o = pr - ln * C;
        float4 t4 = make_float4(0.f, 0.f, 0.f, 0.f);
        float t1 = 0.f;
#pragma unroll
        for (int i = 0; i < FNODE; ++i) {
            const float hv = sx[ln][i];
            const float4 w = sW4[i * C + o];
            t4.x = fmaf(hv, w.x, t4.x);
            t4.y = fmaf(hv, w.y, t4.y);
            t4.z = fmaf(hv, w.z, t4.z);
            t4.w = fmaf(hv, w.w, t4.w);
            t1 = fmaf(hv, sW1[i * C + o], t1);
        }
        const int n = n0 + ln;
        T[n * TW + 0 * C + o] = t4.x;
        T[n * TW + 1 * C + o] = t4.y;
        T[n * TW + 2 * C + o] = t4.z;
        T[n * TW + 3 * C + o] = t4.w;
        T[n * TW + 4 * C + o] = t1;
    }
}

// ---------- gather helper: ELL edges + (empty) overflow list ----------
// unroll 8: ~2 batches of 8 independent ell loads + 40 T-loads in flight
// (gather is L3-latency-bound; MLP is the lever, not instruction count).
__device__ __forceinline__ float gather_max(const float* __restrict__ T_in,
                                            int n, int deg, int o) {
    float acc = -INFINITY;
    const int ke = min(deg, CAP);
    const int base = n * CAP;
#pragma unroll 8
    for (int k = 0; k < ke; ++k) {
        const int soff = g_ell_src[base + k];
        const float4 a = g_ell_ea[base + k];
        const float* __restrict__ Tr = T_in + soff;
        float m = Tr[4 * C + o];
        m = fmaf(a.x, Tr[0 * C + o], m);
        m = fmaf(a.y, Tr[1 * C + o], m);
        m = fmaf(a.z, Tr[2 * C + o], m);
        m = fmaf(a.w, Tr[3 * C + o], m);
        acc = fmaxf(acc, m);
    }
    const int oc = min(g_ovf_cnt, OVF_MAX);   // 0 in practice: one cached load
    for (int p = 0; p < oc; ++p) {
        if (g_ovf_d[p] == n) {
            const float4 a = g_ovf_ea[p];
            const float* __restrict__ Tr = T_in + g_ovf_src[p];
            float m = Tr[4 * C + o];
            m = fmaf(a.x, Tr[0 * C + o], m);
            m = fmaf(a.y, Tr[1 * C + o], m);
            m = fmaf(a.z, Tr[2 * C + o], m);
            m = fmaf(a.w, Tr[3 * C + o], m);
            acc = fmaxf(acc, m);
        }
    }
    return acc;
}

// ---------- 2-5. fused layer (gather + node update + packed-LDS projection) ----------
template <int IN_C>
__global__ void __launch_bounds__(384)
layer_kernel(const float* __restrict__ T_in, const float* __restrict__ h_in,
             const float* __restrict__ root, const float* __restrict__ bias,
             const float* __restrict__ Wn, const float* __restrict__ bn,
             float* __restrict__ h_out, float* __restrict__ T_out) {
    __shared__ float4 sW4[C * C];    // [i][o] -> {ew_f0,ew_f1,ew_f2,ew_f3}
    __shared__ float  sW1[C * C];    // [i][o] -> ebias slice
    __shared__ float  sroot[IN_C * C];
    __shared__ float  sbias[C];
    __shared__ float  shin[16][IN_C];
    __shared__ float  shh[16][C];
    const int o = threadIdx.x;      // 0..23
    const int ty = threadIdx.y;     // 0..15
    const int tid = o + C * ty;
    for (int idx = tid; idx < C * C; idx += 384) {
        sW4[idx] = make_float4(Wn[0 * C * C + idx], Wn[1 * C * C + idx],
                               Wn[2 * C * C + idx], Wn[3 * C * C + idx]);
        sW1[idx] = bn[idx];
    }
    for (int idx = tid; idx < IN_C * C; idx += 384) sroot[idx] = root[idx];
    if (tid < C) sbias[tid] = bias[tid];
    const int n = blockIdx.x * 16 + ty;
    if (o < IN_C) shin[ty][o] = h_in[n * IN_C + o];
    __syncthreads();

    const int deg = g_cnt[n];
    const float acc = gather_max(T_in, n, deg, o);
    float r = sbias[o];
#pragma unroll
    for (int i = 0; i < IN_C; ++i) r = fmaf(shin[ty][i], sroot[i * C + o], r);
    const float h = fminf(fmaxf(((deg == 0) ? 0.f : acc) + r, 0.f), 6.f);
    h_out[n * C + o] = h;
    shh[ty][o] = h;
    __syncthreads();

    // projection: channel o, all 5 f-slices; 1 bcast + b128 + b32 per i
    float4 t4 = make_float4(0.f, 0.f, 0.f, 0.f);
    float t1 = 0.f;
#pragma unroll
    for (int i = 0; i < C; ++i) {
        const float hv = shh[ty][i];
        const float4 w = sW4[i * C + o];
        t4.x = fmaf(hv, w.x, t4.x);
        t4.y = fmaf(hv, w.y, t4.y);
        t4.z = fmaf(hv, w.z, t4.z);
        t4.w = fmaf(hv, w.w, t4.w);
        t1 = fmaf(hv, sW1[i * C + o], t1);
    }
    T_out[n * TW + 0 * C + o] = t4.x;
    T_out[n * TW + 1 * C + o] = t4.y;
    T_out[n * TW + 2 * C + o] = t4.z;
    T_out[n * TW + 3 * C + o] = t4.w;
    T_out[n * TW + 4 * C + o] = t1;
}

// ---------- 6. last layer + head stage-1; re-zeros g_cnt AFTER barrier ----------
__global__ void __launch_bounds__(384)
layer_head_kernel(const float* __restrict__ T_in, const float* __restrict__ h_in,
                  const float* __restrict__ root, const float* __restrict__ bias,
                  const float* __restrict__ w1, float* __restrict__ partial) {
    __shared__ float sroot[C * C];
    __shared__ float sbias[C];
    __shared__ float shin[16][C];
    __shared__ float sred[6][HID];
    const int o = threadIdx.x;
    const int ty = threadIdx.y;
    const int tid = o + C * ty;
    for (int idx = tid; idx < C * C; idx += 384) sroot[idx] = root[idx];
    if (tid < C) sbias[tid] = bias[tid];
    const int n = blockIdx.x * 16 + ty;
    shin[ty][o] = h_in[n * C + o];
    const int deg = g_cnt[n];            // read BEFORE the barrier...
    __syncthreads();
    if (o == 0) g_cnt[n] = 0;            // ...reset AFTER: all reads complete.

    const float acc = gather_max(T_in, n, deg, o);
    float r = sbias[o];
#pragma unroll
    for (int i = 0; i < C; ++i) r = fmaf(shin[ty][i], sroot[i * C + o], r);
    const float h = fminf(fmaxf(((deg == 0) ? 0.f : acc) + r, 0.f), 6.f);

    // head partial: row k = n*C+o of w1 (64 B, coalesced across consecutive o)
    float hacc[HID];
    const float4* wp = (const float4*)(w1 + (size_t)(n * C + o) * HID);
#pragma unroll
    for (int q = 0; q < 4; ++q) {
        const float4 w = wp[q];
        hacc[q * 4 + 0] = h * w.x;
        hacc[q * 4 + 1] = h * w.y;
        hacc[q * 4 + 2] = h * w.z;
        hacc[q * 4 + 3] = h * w.w;
    }
#pragma unroll
    for (int m = 1; m < 64; m <<= 1) {
#pragma unroll
        for (int j = 0; j < HID; ++j) hacc[j] += __shfl_xor(hacc[j], m, 64);
    }
    const int wid = tid >> 6, lane = tid & 63;
    if (lane < HID) sred[wid][lane] = hacc[lane];
    __syncthreads();
    if (tid < HID) {
        float ssum = 0.f;
#pragma unroll
        for (int w = 0; w < 6; ++w) ssum += sred[w][tid];
        partial[blockIdx.x * HID + tid] = ssum;
    }
}

// ---------- 7. head stage-2; re-zeros g_ovf_cnt for next call ----------
__global__ void __launch_bounds__(256)
head2_kernel(const float* __restrict__ partial, const float* __restrict__ b1,
             const float* __restrict__ w2, const float* __restrict__ b2,
             float* __restrict__ out) {
    __shared__ float s[16][HID];
    __shared__ float hid[HID];
    const int j = threadIdx.x & 15, seg = threadIdx.x >> 4;   // 16 segs x 16 ch
    float a = 0.f;
    for (int p = seg; p < NB_L; p += 16) a += partial[p * HID + j];
    s[seg][j] = a;
    __syncthreads();
    if (threadIdx.x < HID) {
        float v = b1[threadIdx.x];
#pragma unroll
        for (int q = 0; q < 16; ++q) v += s[q][threadIdx.x];
        hid[threadIdx.x] = (v > 0.f) ? v : expm1f(v);
    }
    __syncthreads();
    if (threadIdx.x == 0) {
        float v = b2[0];
#pragma unroll
        for (int q = 0; q < HID; ++q) v += hid[q] * w2[q];
        out[0] = (v > 0.f) ? v : expm1f(v);
        g_ovf_cnt = 0;                    // restore invariant
    }
}

extern "C" void kernel_launch(void* const* d_in, const int* in_sizes, int n_in,
                              void* d_out, int out_size, void* d_ws, size_t ws_size,
                              hipStream_t stream) {
    const float* x      = (const float*)d_in[0];
    const float* ea     = (const float*)d_in[1];
    const int*   ei     = (const int*)d_in[2];
    const float* few    = (const float*)d_in[3];
    const float* feb    = (const float*)d_in[4];
    const float* ew     = (const float*)d_in[5];
    const float* ebias  = (const float*)d_in[6];
    const float* root0  = (const float*)d_in[7];
    const float* bias0  = (const float*)d_in[8];
    const float* roots  = (const float*)d_in[9];
    const float* biases = (const float*)d_in[10];
    const float* w1     = (const float*)d_in[11];
    const float* b1     = (const float*)d_in[12];
    const float* w2     = (const float*)d_in[13];
    const float* b2     = (const float*)d_in[14];
    float* out = (float*)d_out;

    const int* src = ei;
    const int* dst = ei + N_EDGES;

    void *pTA_, *pTB_, *pA_, *pB_, *pPart_;
    hipGetSymbolAddress(&pTA_, HIP_SYMBOL(g_TA));
    hipGetSymbolAddress(&pTB_, HIP_SYMBOL(g_TB));
    hipGetSymbolAddress(&pA_,  HIP_SYMBOL(g_hA));
    hipGetSymbolAddress(&pB_,  HIP_SYMBOL(g_hB));
    hipGetSymbolAddress(&pPart_, HIP_SYMBOL(g_partial));
    float* TA = (float*)pTA_;
    float* TB = (float*)pTB_;
    float* hA = (float*)pA_;
    float* hB = (float*)pB_;
    float* partial = (float*)pPart_;

    build_tmat_kernel<<<NB_L, 256, 0, stream>>>(src, dst, ea, x, few, feb, TA);

    dim3 lblk(C, 16);
    layer_kernel<FNODE><<<NB_L, lblk, 0, stream>>>(
        TA, x, root0, bias0, ew, ebias, hA, TB);
    layer_kernel<C><<<NB_L, lblk, 0, stream>>>(
        TB, hA, roots + 0 * C * C, biases + 0 * C, ew, ebias, hB, TA);
    layer_kernel<C><<<NB_L, lblk, 0, stream>>>(
        TA, hB, roots + 1 * C * C, biases + 1 * C, ew, ebias, hA, TB);
    layer_kernel<C><<<NB_L, lblk, 0, stream>>>(
        TB, hA, roots + 2 * C * C, biases + 2 * C, ew, ebias, hB, TA);
    layer_head_kernel<<<NB_L, lblk, 0, stream>>>(
        TA, hB, roots + 3 * C * C, biases + 3 * C, w1, partial);

    head2_kernel<<<1, 256, 0, stream>>>(partial, b1, w2, b2, out);
}

// Round 28
// 118.359 us; speedup vs baseline: 1.3822x; 1.3822x over previous
//
#include <hip/hip_runtime.h>

#define N_NODES 10000
#define N_EDGES 160000
#define FNODE 8
#define C 24
#define HID 16
#define TW (5 * C)    // 120: per-node T row = [f=0..3 ea-weighted][f=4 bias part]
#define NB_L 625      // 625*16 nodes, 625*256 edges exact
#define CAP 64        // ELL capacity; P(Poisson(16) >= 64) ~ 1e-17
#define OVF_MAX 256

// Module-owned scratch. Invariants at call entry: g_cnt == 0 (zero-init at
// load; layer_head re-zeros AFTER a barrier), g_ovf_cnt == 0 (head2 re-zeros).
// Everything else fully rewritten every call. No device-scope fences anywhere.
__device__ int    g_cnt[N_NODES];
__device__ int    g_ell_src[N_NODES * CAP];   // premultiplied: src * TW
__device__ float4 g_ell_ea[N_NODES * CAP];
__device__ int    g_ovf_cnt;
__device__ int    g_ovf_d[OVF_MAX];
__device__ int    g_ovf_src[OVF_MAX];         // premultiplied: src * TW
__device__ float4 g_ovf_ea[OVF_MAX];
__device__ float  g_TA[N_NODES * TW];
__device__ float  g_TB[N_NODES * TW];
__device__ float  g_hA[N_NODES * C];
__device__ float  g_hB[N_NODES * C];
__device__ float  g_partial[NB_L * HID];

// ---------- 1. ELL build (edge binning) + tmat0 (packed-LDS), one dispatch ----------
__global__ void __launch_bounds__(256)
build_tmat_kernel(const int* __restrict__ src, const int* __restrict__ dst,
                  const float* __restrict__ ea, const float* __restrict__ x,
                  const float* __restrict__ few, const float* __restrict__ feb,
                  float* __restrict__ T) {
    __shared__ float4 sW4[FNODE * C];   // [i][o] -> {W_f0,W_f1,W_f2,W_f3}
    __shared__ float  sW1[FNODE * C];   // [i][o] -> bias-proj slice
    __shared__ float  sx[16][FNODE];
    const int tid = threadIdx.x;
    const int b = blockIdx.x;
    for (int idx = tid; idx < FNODE * C; idx += 256) {
        sW4[idx] = make_float4(few[0 * FNODE * C + idx], few[1 * FNODE * C + idx],
                               few[2 * FNODE * C + idx], few[3 * FNODE * C + idx]);
        sW1[idx] = feb[idx];
    }
    const int n0 = b * 16;                  // 625*16 == N_NODES exact
    if (tid < 16 * FNODE) sx[tid / FNODE][tid % FNODE] = x[n0 * FNODE + tid];

    const int e = b * 256 + tid;            // 625*256 == N_EDGES exact
    const int d = dst[e];
    const int slot = atomicAdd(&g_cnt[d], 1);
    if (slot < CAP) {
        g_ell_src[d * CAP + slot] = src[e] * TW;
        g_ell_ea[d * CAP + slot] = ((const float4*)ea)[e];
    } else {
        const int p = atomicAdd(&g_ovf_cnt, 1);
        if (p < OVF_MAX) {
            g_ovf_d[p] = d;
            g_ovf_src[p] = src[e] * TW;
            g_ovf_ea[p] = ((const float4*)ea)[e];
        }
    }
    __syncthreads();
    for (int pr = tid; pr < 16 * C; pr += 256) {
        const int ln = pr / C, o = pr - ln * C;
        float4 t4 = make_float4(0.f, 0.f, 0.f, 0.f);
        float t1 = 0.f;
#pragma unroll
        for (int i = 0; i < FNODE; ++i) {
            const float hv = sx[ln][i];
            const float4 w = sW4[i * C + o];
            t4.x = fmaf(hv, w.x, t4.x);
            t4.y = fmaf(hv, w.y, t4.y);
            t4.z = fmaf(hv, w.z, t4.z);
            t4.w = fmaf(hv, w.w, t4.w);
            t1 = fmaf(hv, sW1[i * C + o], t1);
        }
        const int n = n0 + ln;
        T[n * TW + 0 * C + o] = t4.x;
        T[n * TW + 1 * C + o] = t4.y;
        T[n * TW + 2 * C + o] = t4.z;
        T[n * TW + 3 * C + o] = t4.w;
        T[n * TW + 4 * C + o] = t1;
    }
}

// ---------- gather helper: ELL edges + (empty) overflow list ----------
// unroll 4: measured sweet spot (unroll 8 regressed 118->164 us: remainder
// branches + register pressure; split-T regressed too). Latency-equilibrium.
__device__ __forceinline__ float gather_max(const float* __restrict__ T_in,
                                            int n, int deg, int o) {
    float acc = -INFINITY;
    const int ke = min(deg, CAP);
    const int base = n * CAP;
#pragma unroll 4
    for (int k = 0; k < ke; ++k) {
        const int soff = g_ell_src[base + k];
        const float4 a = g_ell_ea[base + k];
        const float* __restrict__ Tr = T_in + soff;
        float m = Tr[4 * C + o];
        m = fmaf(a.x, Tr[0 * C + o], m);
        m = fmaf(a.y, Tr[1 * C + o], m);
        m = fmaf(a.z, Tr[2 * C + o], m);
        m = fmaf(a.w, Tr[3 * C + o], m);
        acc = fmaxf(acc, m);
    }
    const int oc = min(g_ovf_cnt, OVF_MAX);   // 0 in practice: one cached load
    for (int p = 0; p < oc; ++p) {
        if (g_ovf_d[p] == n) {
            const float4 a = g_ovf_ea[p];
            const float* __restrict__ Tr = T_in + g_ovf_src[p];
            float m = Tr[4 * C + o];
            m = fmaf(a.x, Tr[0 * C + o], m);
            m = fmaf(a.y, Tr[1 * C + o], m);
            m = fmaf(a.z, Tr[2 * C + o], m);
            m = fmaf(a.w, Tr[3 * C + o], m);
            acc = fmaxf(acc, m);
        }
    }
    return acc;
}

// ---------- 2-5. fused layer (gather + node update + packed-LDS projection) ----------
template <int IN_C>
__global__ void __launch_bounds__(384)
layer_kernel(const float* __restrict__ T_in, const float* __restrict__ h_in,
             const float* __restrict__ root, const float* __restrict__ bias,
             const float* __restrict__ Wn, const float* __restrict__ bn,
             float* __restrict__ h_out, float* __restrict__ T_out) {
    __shared__ float4 sW4[C * C];    // [i][o] -> {ew_f0,ew_f1,ew_f2,ew_f3}
    __shared__ float  sW1[C * C];    // [i][o] -> ebias slice
    __shared__ float  sroot[IN_C * C];
    __shared__ float  sbias[C];
    __shared__ float  shin[16][IN_C];
    __shared__ float  shh[16][C];
    const int o = threadIdx.x;      // 0..23
    const int ty = threadIdx.y;     // 0..15
    const int tid = o + C * ty;
    for (int idx = tid; idx < C * C; idx += 384) {
        sW4[idx] = make_float4(Wn[0 * C * C + idx], Wn[1 * C * C + idx],
                               Wn[2 * C * C + idx], Wn[3 * C * C + idx]);
        sW1[idx] = bn[idx];
    }
    for (int idx = tid; idx < IN_C * C; idx += 384) sroot[idx] = root[idx];
    if (tid < C) sbias[tid] = bias[tid];
    const int n = blockIdx.x * 16 + ty;
    if (o < IN_C) shin[ty][o] = h_in[n * IN_C + o];
    __syncthreads();

    const int deg = g_cnt[n];
    const float acc = gather_max(T_in, n, deg, o);
    float r = sbias[o];
#pragma unroll
    for (int i = 0; i < IN_C; ++i) r = fmaf(shin[ty][i], sroot[i * C + o], r);
    const float h = fminf(fmaxf(((deg == 0) ? 0.f : acc) + r, 0.f), 6.f);
    h_out[n * C + o] = h;
    shh[ty][o] = h;
    __syncthreads();

    // projection: channel o, all 5 f-slices; 1 bcast + b128 + b32 per i
    float4 t4 = make_float4(0.f, 0.f, 0.f, 0.f);
    float t1 = 0.f;
#pragma unroll
    for (int i = 0; i < C; ++i) {
        const float hv = shh[ty][i];
        const float4 w = sW4[i * C + o];
        t4.x = fmaf(hv, w.x, t4.x);
        t4.y = fmaf(hv, w.y, t4.y);
        t4.z = fmaf(hv, w.z, t4.z);
        t4.w = fmaf(hv, w.w, t4.w);
        t1 = fmaf(hv, sW1[i * C + o], t1);
    }
    T_out[n * TW + 0 * C + o] = t4.x;
    T_out[n * TW + 1 * C + o] = t4.y;
    T_out[n * TW + 2 * C + o] = t4.z;
    T_out[n * TW + 3 * C + o] = t4.w;
    T_out[n * TW + 4 * C + o] = t1;
}

// ---------- 6. last layer + head stage-1; re-zeros g_cnt AFTER barrier ----------
__global__ void __launch_bounds__(384)
layer_head_kernel(const float* __restrict__ T_in, const float* __restrict__ h_in,
                  const float* __restrict__ root, const float* __restrict__ bias,
                  const float* __restrict__ w1, float* __restrict__ partial) {
    __shared__ float sroot[C * C];
    __shared__ float sbias[C];
    __shared__ float shin[16][C];
    __shared__ float sred[6][HID];
    const int o = threadIdx.x;
    const int ty = threadIdx.y;
    const int tid = o + C * ty;
    for (int idx = tid; idx < C * C; idx += 384) sroot[idx] = root[idx];
    if (tid < C) sbias[tid] = bias[tid];
    const int n = blockIdx.x * 16 + ty;
    shin[ty][o] = h_in[n * C + o];
    const int deg = g_cnt[n];            // read BEFORE the barrier...
    __syncthreads();
    if (o == 0) g_cnt[n] = 0;            // ...reset AFTER: all reads complete.

    const float acc = gather_max(T_in, n, deg, o);
    float r = sbias[o];
#pragma unroll
    for (int i = 0; i < C; ++i) r = fmaf(shin[ty][i], sroot[i * C + o], r);
    const float h = fminf(fmaxf(((deg == 0) ? 0.f : acc) + r, 0.f), 6.f);

    // head partial: row k = n*C+o of w1 (64 B, coalesced across consecutive o)
    float hacc[HID];
    const float4* wp = (const float4*)(w1 + (size_t)(n * C + o) * HID);
#pragma unroll
    for (int q = 0; q < 4; ++q) {
        const float4 w = wp[q];
        hacc[q * 4 + 0] = h * w.x;
        hacc[q * 4 + 1] = h * w.y;
        hacc[q * 4 + 2] = h * w.z;
        hacc[q * 4 + 3] = h * w.w;
    }
#pragma unroll
    for (int m = 1; m < 64; m <<= 1) {
#pragma unroll
        for (int j = 0; j < HID; ++j) hacc[j] += __shfl_xor(hacc[j], m, 64);
    }
    const int wid = tid >> 6, lane = tid & 63;
    if (lane < HID) sred[wid][lane] = hacc[lane];
    __syncthreads();
    if (tid < HID) {
        float ssum = 0.f;
#pragma unroll
        for (int w = 0; w < 6; ++w) ssum += sred[w][tid];
        partial[blockIdx.x * HID + tid] = ssum;
    }
}

// ---------- 7. head stage-2; re-zeros g_ovf_cnt for next call ----------
__global__ void __launch_bounds__(256)
head2_kernel(const float* __restrict__ partial, const float* __restrict__ b1,
             const float* __restrict__ w2, const float* __restrict__ b2,
             float* __restrict__ out) {
    __shared__ float s[16][HID];
    __shared__ float hid[HID];
    const int j = threadIdx.x & 15, seg = threadIdx.x >> 4;   // 16 segs x 16 ch
    float a = 0.f;
    for (int p = seg; p < NB_L; p += 16) a += partial[p * HID + j];
    s[seg][j] = a;
    __syncthreads();
    if (threadIdx.x < HID) {
        float v = b1[threadIdx.x];
#pragma unroll
        for (int q = 0; q < 16; ++q) v += s[q][threadIdx.x];
        hid[threadIdx.x] = (v > 0.f) ? v : expm1f(v);
    }
    __syncthreads();
    if (threadIdx.x == 0) {
        float v = b2[0];
#pragma unroll
        for (int q = 0; q < HID; ++q) v += hid[q] * w2[q];
        out[0] = (v > 0.f) ? v : expm1f(v);
        g_ovf_cnt = 0;                    // restore invariant
    }
}

extern "C" void kernel_launch(void* const* d_in, const int* in_sizes, int n_in,
                              void* d_out, int out_size, void* d_ws, size_t ws_size,
                              hipStream_t stream) {
    const float* x      = (const float*)d_in[0];
    const float* ea     = (const float*)d_in[1];
    const int*   ei     = (const int*)d_in[2];
    const float* few    = (const float*)d_in[3];
    const float* feb    = (const float*)d_in[4];
    const float* ew     = (const float*)d_in[5];
    const float* ebias  = (const float*)d_in[6];
    const float* root0  = (const float*)d_in[7];
    const float* bias0  = (const float*)d_in[8];
    const float* roots  = (const float*)d_in[9];
    const float* biases = (const float*)d_in[10];
    const float* w1     = (const float*)d_in[11];
    const float* b1     = (const float*)d_in[12];
    const float* w2     = (const float*)d_in[13];
    const float* b2     = (const float*)d_in[14];
    float* out = (float*)d_out;

    const int* src = ei;
    const int* dst = ei + N_EDGES;

    void *pTA_, *pTB_, *pA_, *pB_, *pPart_;
    hipGetSymbolAddress(&pTA_, HIP_SYMBOL(g_TA));
    hipGetSymbolAddress(&pTB_, HIP_SYMBOL(g_TB));
    hipGetSymbolAddress(&pA_,  HIP_SYMBOL(g_hA));
    hipGetSymbolAddress(&pB_,  HIP_SYMBOL(g_hB));
    hipGetSymbolAddress(&pPart_, HIP_SYMBOL(g_partial));
    float* TA = (float*)pTA_;
    float* TB = (float*)pTB_;
    float* hA = (float*)pA_;
    float* hB = (float*)pB_;
    float* partial = (float*)pPart_;

    build_tmat_kernel<<<NB_L, 256, 0, stream>>>(src, dst, ea, x, few, feb, TA);

    dim3 lblk(C, 16);
    layer_kernel<FNODE><<<NB_L, lblk, 0, stream>>>(
        TA, x, root0, bias0, ew, ebias, hA, TB);
    layer_kernel<C><<<NB_L, lblk, 0, stream>>>(
        TB, hA, roots + 0 * C * C, biases + 0 * C, ew, ebias, hB, TA);
    layer_kernel<C><<<NB_L, lblk, 0, stream>>>(
        TA, hB, roots + 1 * C * C, biases + 1 * C, ew, ebias, hA, TB);
    layer_kernel<C><<<NB_L, lblk, 0, stream>>>(
        TB, hA, roots + 2 * C * C, biases + 2 * C, ew, ebias, hB, TA);
    layer_head_kernel<<<NB_L, lblk, 0, stream>>>(
        TA, hB, roots + 3 * C * C, biases + 3 * C, w1, partial);

    head2_kernel<<<1, 256, 0, stream>>>(partial, b1, w2, b2, out);
}